// Round 13
// baseline (673.941 us; speedup 1.0000x reference)
//
#include <hip/hip_runtime.h>
#include <hip/hip_bf16.h>
#include <stdint.h>

#define IN_SZ 128
#define HID 128
#define OUT_SZ 67
#define SEQ 512
#define BATCH 2048
#define BT 8
#define NTHR 512
#define SB (SEQ * BATCH)   // 1048576

typedef __attribute__((ext_vector_type(4))) float f32x4;
typedef __attribute__((ext_vector_type(8))) short s16x8;
typedef __attribute__((ext_vector_type(8))) __bf16 bf16x8;

typedef const uint32_t __attribute__((address_space(1))) gu32_t;
typedef uint32_t __attribute__((address_space(3))) su32_t;

static __device__ __forceinline__ unsigned short f2bf(float f) {
  union { float f; uint32_t u; } c; c.f = f;
  uint32_t u = c.u;
  uint32_t r = u + 0x7FFFu + ((u >> 16) & 1u);
  return (unsigned short)(r >> 16);
}
static __device__ __forceinline__ uint32_t pk2bf(float lo, float hi) {
  __hip_bfloat162 h2 = __float22bfloat162_rn(float2{lo, hi});
  union { __hip_bfloat162 h; uint32_t u; } c; c.h = h2;
  return c.u;
}
static __device__ __forceinline__ float fast_tanh(float x) {
  float e = __builtin_amdgcn_exp2f(x * 2.885390081777927f);
  float r = __builtin_amdgcn_rcpf(e + 1.f);
  return __builtin_fmaf(-2.f, r, 1.f);
}
static __device__ __forceinline__ void mfma16(f32x4& c, s16x8 a, s16x8 b) {
  c = __builtin_amdgcn_mfma_f32_16x16x32_bf16(
        __builtin_bit_cast(bf16x8, a), __builtin_bit_cast(bf16x8, b), c, 0, 0, 0);
}
#define KOFF(g, j) (4 * (g) + ((j) & 3) + (((j) >> 2) << 4))

// clobber-free barrier (validated R9-R12)
static __device__ __forceinline__ void frag_barrier() {
  asm volatile("s_waitcnt lgkmcnt(0)");
  __builtin_amdgcn_s_barrier();
}
// async global->LDS DMA, 4 bytes per lane (dest = uniform base + lane*4)
static __device__ __forceinline__ void dma4(const float* src, float* dst) {
  __builtin_amdgcn_global_load_lds((gu32_t*)(const void*)src,
                                   (su32_t*)(void*)dst, 4, 0, 0);
}

__global__ __launch_bounds__(NTHR, 1) void rnn_kernel(
    const float* __restrict__ x, const float* __restrict__ hidden,
    const float* __restrict__ mask, const float* __restrict__ Wi2h,
    const float* __restrict__ bi2h, const float* __restrict__ Wi2o,
    const float* __restrict__ bi2o, float* __restrict__ Y) {

  __shared__ s16x8 sF[2][8][64];   // [buf][0..3 x kk, 4..7 h kk][lane]; 16 KB
  __shared__ float sX[4][1024];    // raw f32 x ring, elem = row*8 + col; 16 KB

  const int tid = threadIdx.x;
  const int wave = tid >> 6;      // 0..7; owns i2h M-tile `wave`
  const int lane = tid & 63;
  const int g = lane >> 4;
  const int n16 = lane & 15;
  const int bid = ((blockIdx.x & 7) << 5) | (blockIdx.x >> 3);  // XCD-chunk swizzle
  const int b0 = bid * BT;

  // ---- Wi2h A-frags for tile `wave` (32 VGPR) ----
  s16x8 W[8];
#pragma unroll
  for (int kt = 0; kt < 8; ++kt) {
    const float* wr = Wi2h + (size_t)(16 * wave + n16) * (IN_SZ + HID);
    s16x8 w8;
#pragma unroll
    for (int j = 0; j < 8; ++j)
      w8[j] = (short)f2bf(wr[32 * kt + KOFF(g, j)]);
    W[kt] = w8;
  }

  // ---- i2o frags: waves 0..4 own out-tile = wave ----
  const bool hasO = (wave < 5);
  s16x8 wO[4];
#pragma unroll
  for (int kk = 0; kk < 4; ++kk) {
    s16x8 a;
#pragma unroll
    for (int j = 0; j < 8; ++j) {
      int m = 16 * wave + n16;
      a[j] = (short)((hasO && m < OUT_SZ)
                     ? f2bf(Wi2o[(size_t)m * HID + 32 * kk + KOFF(g, j)]) : 0);
    }
    wO[kk] = a;
  }

  f32x4 bhv, bov;
#pragma unroll
  for (int r = 0; r < 4; ++r) {
    bhv[r] = bi2h[16 * wave + 4 * g + r];
    int m = 16 * wave + 4 * g + r;
    bov[r] = (hasO && m < OUT_SZ) ? bi2o[m] : 0.f;
  }

  // ---- DMA source pointers (per lane): rows 16w+8q+(l>>3), col l&7 ----
  const float* dma0 = x + (size_t)(16 * wave + (lane >> 3)) * SB + b0 + (lane & 7);
  const float* dma1 = dma0 + (size_t)8 * SB;

  // ---- loader/consumer mapping (validated R12): rows 2*lrb, 2*lrb+1 ----
  const int lc = tid & 7;
  const int lrb = tid >> 3;                 // 0..63
  const int R0 = 2 * lrb;
  const int skk = R0 >> 5;
  const int r5 = R0 & 31;
  const int sg = (r5 < 16) ? (r5 >> 2) : ((r5 - 16) >> 2);
  const int sq = ((r5 & 2) >> 1) + ((r5 < 16) ? 0 : 2);
  const int slane = (sg << 4) | lc;
  const int e0 = R0 * 8 + lc;               // sX elem of row R0 (row R0+1 = +8)

  // ---- stage x_0, h_0 frags into buf 0 (direct loads) ----
  {
    float v0 = x[(size_t)R0 * SB + b0 + lc];
    float v1 = x[(size_t)(R0 + 1) * SB + b0 + lc];
    ((uint32_t*)&sF[0][skk][slane])[sq] = pk2bf(v0, v1);
    uint32_t h0o = (uint32_t)R0 * (uint32_t)BATCH + (uint32_t)(b0 + lc);
    uint32_t h1o = (uint32_t)(R0 + 1) * (uint32_t)BATCH + (uint32_t)(b0 + lc);
    float hv0 = hidden[(size_t)h0o] * mask[(size_t)h0o];
    float hv1 = hidden[(size_t)h1o] * mask[(size_t)h1o];
    ((uint32_t*)&sF[0][4 + skk][slane])[sq] = pk2bf(hv0, hv1);
  }

#define STAGE(T, D)                                                             \
  {                                                                             \
    const uint32_t tp = ((T) > 511 ? 511u : (uint32_t)(T)) * (uint32_t)BATCH;   \
    dma4(dma0 + tp, &sX[D][128 * wave]);                                        \
    dma4(dma1 + tp, &sX[D][128 * wave + 64]);                                   \
  }

  // prologue DMAs: x_1, x_2, x_3 into ring slots 1,2,3
  STAGE(1, 1)
  STAGE(2, 2)
  STAGE(3, 3)
  frag_barrier();

  const uint32_t ybase = (uint32_t)(16 * wave + 4 * g) * (uint32_t)SB + (uint32_t)(b0 + n16);
  uint32_t* const hdst0 = (uint32_t*)&sF[0][4 + (wave >> 1)][lane] + (wave & 1) * 2;
  uint32_t* const hdst1 = (uint32_t*)&sF[1][4 + (wave >> 1)][lane] + (wave & 1) * 2;

#define STEP(T, P, D)                                                           \
  {                                                                             \
    const int t = (T);                                                          \
    const int pn = (P) ^ 1;                                                     \
    /* 1. frags of [x_t ; h_t] from buf P */                                    \
    s16x8 X0 = sF[P][0][lane], X1 = sF[P][1][lane];                             \
    s16x8 X2 = sF[P][2][lane], X3 = sF[P][3][lane];                             \
    s16x8 H0 = sF[P][4][lane], H1 = sF[P][5][lane];                             \
    s16x8 H2 = sF[P][6][lane], H3 = sF[P][7][lane];                             \
    /* 2. i2h: 4 independent chains of depth 2 */                               \
    f32x4 a = bhv, a2 = {0.f, 0.f, 0.f, 0.f};                                   \
    f32x4 ax = {0.f, 0.f, 0.f, 0.f}, ax2 = {0.f, 0.f, 0.f, 0.f};                \
    mfma16(a, W[4], H0);   mfma16(a2, W[5], H1);                                \
    mfma16(ax, W[0], X0);  mfma16(ax2, W[1], X1);                               \
    mfma16(a, W[6], H2);   mfma16(a2, W[7], H3);                                \
    mfma16(ax, W[2], X2);  mfma16(ax2, W[3], X3);                               \
    /* 3. h_{t+1} = tanh(sum); write half-frag via D-frag==B-frag identity */   \
    {                                                                           \
      f32x4 s0 = (a + a2) + (ax + ax2);                                         \
      uint32_t hp[2];                                                           \
      hp[0] = pk2bf(fast_tanh(s0[0]), fast_tanh(s0[1]));                        \
      hp[1] = pk2bf(fast_tanh(s0[2]), fast_tanh(s0[3]));                        \
      uint32_t* hd = pn ? hdst1 : hdst0;                                        \
      *(uint64_t*)hd = *(uint64_t*)hp;                                          \
    }                                                                           \
    /* 4. consume raw x_{t+1} from sX ring (DMA'd 3 iters ago) */               \
    asm volatile("s_waitcnt vmcnt(4)");                                         \
    __builtin_amdgcn_sched_barrier(0);                                          \
    {                                                                           \
      float v0 = sX[D][e0];                                                     \
      float v1 = sX[D][e0 + 8];                                                 \
      ((uint32_t*)&sF[pn][skk][slane])[sq] = pk2bf(v0, v1);                     \
    }                                                                           \
    /* 5. publish buf pn */                                                     \
    frag_barrier();                                                             \
    /* 6. post-barrier: i2o(t-1) on in-reg H; Y stores; DMA x_{t+4} */          \
    if (hasO && t > 0) {                                                        \
      const uint32_t ty = (uint32_t)(t - 1) * (uint32_t)BATCH;                  \
      f32x4 ao = bov;                                                           \
      mfma16(ao, wO[0], H0); mfma16(ao, wO[1], H1);                             \
      mfma16(ao, wO[2], H2); mfma16(ao, wO[3], H3);                             \
      if (n16 < BT) {                                                           \
        _Pragma("unroll")                                                       \
        for (int r = 0; r < 4; ++r)                                             \
          if (16 * wave + 4 * g + r < OUT_SZ)                                   \
            Y[(size_t)(ybase + (uint32_t)r * SB + ty)] = fmaxf(ao[r], 0.f);     \
      }                                                                         \
    }                                                                           \
    STAGE(t + 4, (T) & 3)                                                       \
  }

  for (int t4 = 0; t4 < SEQ; t4 += 4) {
    STEP(t4 + 0, 0, 1);
    STEP(t4 + 1, 1, 2);
    STEP(t4 + 2, 0, 3);
    STEP(t4 + 3, 1, 0);
  }
#undef STEP
#undef STAGE

  // ---- epilogue: y_511 from h_512 (buf 0) ----
  if (hasO) {
    s16x8 H0 = sF[0][4][lane], H1 = sF[0][5][lane];
    s16x8 H2 = sF[0][6][lane], H3 = sF[0][7][lane];
    const uint32_t ty = 511u * (uint32_t)BATCH;
    f32x4 ao = bov;
    mfma16(ao, wO[0], H0); mfma16(ao, wO[1], H1);
    mfma16(ao, wO[2], H2); mfma16(ao, wO[3], H3);
    if (n16 < BT) {
#pragma unroll
      for (int r = 0; r < 4; ++r)
        if (16 * wave + 4 * g + r < OUT_SZ)
          Y[(size_t)(ybase + (uint32_t)r * SB + ty)] = fmaxf(ao[r], 0.f);
    }
  }
}

extern "C" void kernel_launch(void* const* d_in, const int* in_sizes, int n_in,
                              void* d_out, int out_size, void* d_ws, size_t ws_size,
                              hipStream_t stream) {
  const float* x      = (const float*)d_in[0];
  const float* hidden = (const float*)d_in[1];
  const float* mask   = (const float*)d_in[2];
  const float* Wi2h   = (const float*)d_in[3];
  const float* bi2h   = (const float*)d_in[4];
  const float* Wi2o   = (const float*)d_in[5];
  const float* bi2o   = (const float*)d_in[6];
  float* Y = (float*)d_out;
  (void)in_sizes; (void)n_in; (void)out_size; (void)d_ws; (void)ws_size;
  rnn_kernel<<<dim3(BATCH / BT), dim3(NTHR), 0, stream>>>(
      x, hidden, mask, Wi2h, bi2h, Wi2o, bi2o, Y);
}

// Round 14
// 594.582 us; speedup vs baseline: 1.1335x; 1.1335x over previous
//
#include <hip/hip_runtime.h>
#include <hip/hip_bf16.h>
#include <stdint.h>

#define IN_SZ 128
#define HID 128
#define OUT_SZ 67
#define SEQ 512
#define BATCH 2048
#define BT 8
#define NTHR 512
#define SB (SEQ * BATCH)   // 1048576

typedef __attribute__((ext_vector_type(4))) float f32x4;
typedef __attribute__((ext_vector_type(8))) short s16x8;
typedef __attribute__((ext_vector_type(8))) __bf16 bf16x8;

static __device__ __forceinline__ unsigned short f2bf(float f) {
  union { float f; uint32_t u; } c; c.f = f;
  uint32_t u = c.u;
  uint32_t r = u + 0x7FFFu + ((u >> 16) & 1u);
  return (unsigned short)(r >> 16);
}
static __device__ __forceinline__ uint32_t pk2bf(float lo, float hi) {
  __hip_bfloat162 h2 = __float22bfloat162_rn(float2{lo, hi});
  union { __hip_bfloat162 h; uint32_t u; } c; c.h = h2;
  return c.u;
}
static __device__ __forceinline__ float fast_tanh(float x) {
  float e = __builtin_amdgcn_exp2f(x * 2.885390081777927f);
  float r = __builtin_amdgcn_rcpf(e + 1.f);
  return __builtin_fmaf(-2.f, r, 1.f);
}
static __device__ __forceinline__ void mfma16(f32x4& c, s16x8 a, s16x8 b) {
  c = __builtin_amdgcn_mfma_f32_16x16x32_bf16(
        __builtin_bit_cast(bf16x8, a), __builtin_bit_cast(bf16x8, b), c, 0, 0, 0);
}
#define KOFF(g, j) (4 * (g) + ((j) & 3) + (((j) >> 2) << 4))

// clobber-free barrier + sched fences (ds ops must not cross; vm ops may)
static __device__ __forceinline__ void frag_barrier() {
  __builtin_amdgcn_sched_barrier(0);
  asm volatile("s_waitcnt lgkmcnt(0)");
  __builtin_amdgcn_s_barrier();
  __builtin_amdgcn_sched_barrier(0);
}

__global__ __launch_bounds__(NTHR, 1) void rnn_kernel(
    const float* __restrict__ x, const float* __restrict__ hidden,
    const float* __restrict__ mask, const float* __restrict__ Wi2h,
    const float* __restrict__ bi2h, const float* __restrict__ Wi2o,
    const float* __restrict__ bi2o, float* __restrict__ Y) {

  __shared__ s16x8 sH[2][4][64];   // h frags, double buffer; 8 KB
  __shared__ s16x8 sX[3][4][64];   // x frags, triple buffer (staged 2 ahead); 12 KB

  const int tid = threadIdx.x;
  const int wave = tid >> 6;      // 0..7; owns i2h M-tile `wave`
  const int lane = tid & 63;
  const int g = lane >> 4;
  const int n16 = lane & 15;
  const int bid = ((blockIdx.x & 7) << 5) | (blockIdx.x >> 3);  // XCD-chunk swizzle
  const int b0 = bid * BT;

  // ---- Wi2h A-frags for tile `wave` ----
  s16x8 W[8];
#pragma unroll
  for (int kt = 0; kt < 8; ++kt) {
    const float* wr = Wi2h + (size_t)(16 * wave + n16) * (IN_SZ + HID);
    s16x8 w8;
#pragma unroll
    for (int j = 0; j < 8; ++j)
      w8[j] = (short)f2bf(wr[32 * kt + KOFF(g, j)]);
    W[kt] = w8;
  }

  // ---- i2o frags: waves 0..4 own out-tile = wave ----
  const bool hasO = (wave < 5);
  s16x8 wO[4];
#pragma unroll
  for (int kk = 0; kk < 4; ++kk) {
    s16x8 a;
#pragma unroll
    for (int j = 0; j < 8; ++j) {
      int m = 16 * wave + n16;
      a[j] = (short)((hasO && m < OUT_SZ)
                     ? f2bf(Wi2o[(size_t)m * HID + 32 * kk + KOFF(g, j)]) : 0);
    }
    wO[kk] = a;
  }

  f32x4 bhv, bov;
#pragma unroll
  for (int r = 0; r < 4; ++r) {
    bhv[r] = bi2h[16 * wave + 4 * g + r];
    int m = 16 * wave + 4 * g + r;
    bov[r] = (hasO && m < OUT_SZ) ? bi2o[m] : 0.f;
  }

  // ---- loader mapping (validated R12): rows 2*lrb, 2*lrb+1 at col lc ----
  const int lc = tid & 7;
  const int lrb = tid >> 3;
  const int R0 = 2 * lrb;
  const int skk = R0 >> 5;
  const int r5 = R0 & 31;
  const int sg = (r5 < 16) ? (r5 >> 2) : ((r5 - 16) >> 2);
  const int sq = ((r5 & 2) >> 1) + ((r5 < 16) ? 0 : 2);
  const int slane = (sg << 4) | lc;
  const char* const xB = (const char*)x;
  const uint32_t xrb0 = ((uint32_t)R0 * (uint32_t)SB + (uint32_t)(b0 + lc)) * 4u;
  const uint32_t xrb1 = ((uint32_t)(R0 + 1) * (uint32_t)SB + (uint32_t)(b0 + lc)) * 4u;

  // ---- stage X(0)->sX[0], X(1)->sX[1], H(0)->sH[0] ----
  {
    float v0 = *(const float*)(xB + xrb0);
    float v1 = *(const float*)(xB + xrb1);
    ((uint32_t*)&sX[0][skk][slane])[sq] = pk2bf(v0, v1);
    float w0 = *(const float*)(xB + xrb0 + BATCH * 4u);
    float w1 = *(const float*)(xB + xrb1 + BATCH * 4u);
    ((uint32_t*)&sX[1][skk][slane])[sq] = pk2bf(w0, w1);
    uint32_t h0o = (uint32_t)R0 * (uint32_t)BATCH + (uint32_t)(b0 + lc);
    uint32_t h1o = (uint32_t)(R0 + 1) * (uint32_t)BATCH + (uint32_t)(b0 + lc);
    float hv0 = hidden[(size_t)h0o] * mask[(size_t)h0o];
    float hv1 = hidden[(size_t)h1o] * mask[(size_t)h1o];
    ((uint32_t*)&sH[0][skk][slane])[sq] = pk2bf(hv0, hv1);
  }
  // raw prefetch: xqA = x(2), xqB = x(3)
  float xqA[2], xqB[2];
  xqA[0] = *(const float*)(xB + xrb0 + 2u * BATCH * 4u);
  xqA[1] = *(const float*)(xB + xrb1 + 2u * BATCH * 4u);
  xqB[0] = *(const float*)(xB + xrb0 + 3u * BATCH * 4u);
  xqB[1] = *(const float*)(xB + xrb1 + 3u * BATCH * 4u);
  frag_barrier();

  const uint32_t ybase = (uint32_t)(16 * wave + 4 * g) * (uint32_t)SB + (uint32_t)(b0 + n16);
  uint32_t* const hdst0 = (uint32_t*)&sH[0][wave >> 1][lane] + (wave & 1) * 2;
  uint32_t* const hdst1 = (uint32_t*)&sH[1][wave >> 1][lane] + (wave & 1) * 2;

  // ---- pre-loop: ax(0) = bhv + Wx*X(0) ----
  f32x4 axA = bhv, axA2 = {0.f, 0.f, 0.f, 0.f};
  f32x4 axB, axB2;
  {
    s16x8 X0 = sX[0][0][lane], X1 = sX[0][1][lane];
    s16x8 X2 = sX[0][2][lane], X3 = sX[0][3][lane];
    mfma16(axA, W[0], X0);  mfma16(axA2, W[1], X1);
    mfma16(axA, W[2], X2);  mfma16(axA2, W[3], X3);
  }

  // ITER(t): chain = read H(t) -> 4 H-MFMAs into carried ax -> tanh -> write
  // h(t+1). Shadow = ax(t+1) from X(t+1) [slot SR], i2o(t-1) on H regs,
  // stage X(t+2)->slot SW from XQ, reload XQ = x(t+4).
#define ITER(K, SR, SW, HPAR, XQ, AXI, AXI2, AXO, AXO2)                        \
  {                                                                            \
    const int t = t6 + (K);                                                    \
    s16x8 H0 = sH[HPAR][0][lane], H1 = sH[HPAR][1][lane];                      \
    s16x8 H2 = sH[HPAR][2][lane], H3 = sH[HPAR][3][lane];                      \
    s16x8 Xn0 = sX[SR][0][lane], Xn1 = sX[SR][1][lane];                        \
    s16x8 Xn2 = sX[SR][2][lane], Xn3 = sX[SR][3][lane];                        \
    /* chain: H-part (depth 2 per acc) */                                      \
    mfma16(AXI, W[4], H0);   mfma16(AXI2, W[5], H1);                           \
    mfma16(AXI, W[6], H2);   mfma16(AXI2, W[7], H3);                           \
    /* shadow: X-part for step t+1 */                                          \
    AXO = bhv; AXO2 = (f32x4){0.f, 0.f, 0.f, 0.f};                             \
    mfma16(AXO, W[0], Xn0);  mfma16(AXO2, W[1], Xn1);                          \
    mfma16(AXO, W[2], Xn2);  mfma16(AXO2, W[3], Xn3);                          \
    /* chain: tanh + publish h(t+1) half-frag (D-frag == B-frag identity) */   \
    {                                                                          \
      f32x4 s0 = AXI + AXI2;                                                   \
      uint32_t hpq[2];                                                         \
      hpq[0] = pk2bf(fast_tanh(s0[0]), fast_tanh(s0[1]));                      \
      hpq[1] = pk2bf(fast_tanh(s0[2]), fast_tanh(s0[3]));                      \
      *(uint64_t*)((HPAR) ? hdst0 : hdst1) = *(uint64_t*)hpq;                  \
    }                                                                          \
    /* shadow: i2o(t-1) on in-register H(t) */                                 \
    if (hasO && t > 0) {                                                       \
      const uint32_t ty = (uint32_t)(t - 1) * (uint32_t)BATCH;                 \
      f32x4 ao = bov;                                                          \
      mfma16(ao, wO[0], H0); mfma16(ao, wO[1], H1);                            \
      mfma16(ao, wO[2], H2); mfma16(ao, wO[3], H3);                            \
      if (n16 < BT) {                                                          \
        _Pragma("unroll")                                                      \
        for (int r = 0; r < 4; ++r)                                            \
          if (16 * wave + 4 * g + r < OUT_SZ)                                  \
            Y[(size_t)(ybase + (uint32_t)r * SB + ty)] = fmaxf(ao[r], 0.f);    \
      }                                                                        \
    }                                                                          \
    /* shadow: stage X(t+2); reload XQ = x(t+4) */                             \
    ((uint32_t*)&sX[SW][skk][slane])[sq] = pk2bf(XQ[0], XQ[1]);                \
    {                                                                          \
      const uint32_t tn = (uint32_t)((t + 4 > 511) ? 511 : t + 4) * (BATCH * 4u); \
      XQ[0] = *(const float*)(xB + xrb0 + tn);                                 \
      XQ[1] = *(const float*)(xB + xrb1 + tn);                                 \
    }                                                                          \
    frag_barrier();                                                            \
  }

  for (int t6 = 0; t6 < 510; t6 += 6) {
    ITER(0, 1, 2, 0, xqA, axA, axA2, axB, axB2)
    ITER(1, 2, 0, 1, xqB, axB, axB2, axA, axA2)
    ITER(2, 0, 1, 0, xqA, axA, axA2, axB, axB2)
    ITER(3, 1, 2, 1, xqB, axB, axB2, axA, axA2)
    ITER(4, 2, 0, 0, xqA, axA, axA2, axB, axB2)
    ITER(5, 0, 1, 1, xqB, axB, axB2, axA, axA2)
  }
  {  // tail: t = 510, 511 (510 % 6 == 0, pattern continues)
    const int t6 = 510;
    ITER(0, 1, 2, 0, xqA, axA, axA2, axB, axB2)
    ITER(1, 2, 0, 1, xqB, axB, axB2, axA, axA2)
  }
#undef ITER

  // ---- epilogue: y_511 from h_512 (parity 512&1 = 0) ----
  if (hasO) {
    s16x8 H0 = sH[0][0][lane], H1 = sH[0][1][lane];
    s16x8 H2 = sH[0][2][lane], H3 = sH[0][3][lane];
    const uint32_t ty = 511u * (uint32_t)BATCH;
    f32x4 ao = bov;
    mfma16(ao, wO[0], H0); mfma16(ao, wO[1], H1);
    mfma16(ao, wO[2], H2); mfma16(ao, wO[3], H3);
    if (n16 < BT) {
#pragma unroll
      for (int r = 0; r < 4; ++r)
        if (16 * wave + 4 * g + r < OUT_SZ)
          Y[(size_t)(ybase + (uint32_t)r * SB + ty)] = fmaxf(ao[r], 0.f);
    }
  }
}

extern "C" void kernel_launch(void* const* d_in, const int* in_sizes, int n_in,
                              void* d_out, int out_size, void* d_ws, size_t ws_size,
                              hipStream_t stream) {
  const float* x      = (const float*)d_in[0];
  const float* hidden = (const float*)d_in[1];
  const float* mask   = (const float*)d_in[2];
  const float* Wi2h   = (const float*)d_in[3];
  const float* bi2h   = (const float*)d_in[4];
  const float* Wi2o   = (const float*)d_in[5];
  const float* bi2o   = (const float*)d_in[6];
  float* Y = (float*)d_out;
  (void)in_sizes; (void)n_in; (void)out_size; (void)d_ws; (void)ws_size;
  rnn_kernel<<<dim3(BATCH / BT), dim3(NTHR), 0, stream>>>(
      x, hidden, mask, Wi2h, bi2h, Wi2o, bi2o, Y);
}

// Round 15
// 518.375 us; speedup vs baseline: 1.3001x; 1.1470x over previous
//
#include <hip/hip_runtime.h>
#include <hip/hip_bf16.h>
#include <stdint.h>

#define IN_SZ 128
#define HID 128
#define OUT_SZ 67
#define SEQ 512
#define BATCH 2048
#define BT 8
#define NTHR 640   // 8 compute waves + 2 i2o/store waves
#define SB (SEQ * BATCH)   // 1048576

typedef __attribute__((ext_vector_type(4))) float f32x4;
typedef __attribute__((ext_vector_type(8))) short s16x8;
typedef __attribute__((ext_vector_type(8))) __bf16 bf16x8;

static __device__ __forceinline__ unsigned short f2bf(float f) {
  union { float f; uint32_t u; } c; c.f = f;
  uint32_t u = c.u;
  uint32_t r = u + 0x7FFFu + ((u >> 16) & 1u);
  return (unsigned short)(r >> 16);
}
static __device__ __forceinline__ uint32_t pk2bf(float lo, float hi) {
  __hip_bfloat162 h2 = __float22bfloat162_rn(float2{lo, hi});
  union { __hip_bfloat162 h; uint32_t u; } c; c.h = h2;
  return c.u;
}
static __device__ __forceinline__ float fast_tanh(float x) {
  float e = __builtin_amdgcn_exp2f(x * 2.885390081777927f);
  float r = __builtin_amdgcn_rcpf(e + 1.f);
  return __builtin_fmaf(-2.f, r, 1.f);
}
static __device__ __forceinline__ void mfma16(f32x4& c, s16x8 a, s16x8 b) {
  c = __builtin_amdgcn_mfma_f32_16x16x32_bf16(
        __builtin_bit_cast(bf16x8, a), __builtin_bit_cast(bf16x8, b), c, 0, 0, 0);
}
#define KOFF(g, j) (4 * (g) + ((j) & 3) + (((j) >> 2) << 4))

// clobber-free barrier (validated R9-R14): lgkm-only drain; vm ops float across
static __device__ __forceinline__ void frag_barrier() {
  __builtin_amdgcn_sched_barrier(0);
  asm volatile("s_waitcnt lgkmcnt(0)");
  __builtin_amdgcn_s_barrier();
  __builtin_amdgcn_sched_barrier(0);
}

__global__ __launch_bounds__(NTHR, 1) void rnn_kernel(
    const float* __restrict__ x, const float* __restrict__ hidden,
    const float* __restrict__ mask, const float* __restrict__ Wi2h,
    const float* __restrict__ bi2h, const float* __restrict__ Wi2o,
    const float* __restrict__ bi2o, float* __restrict__ Y) {

  __shared__ s16x8 sF[2][8][64];   // [buf][0..3 x kk, 4..7 h kk][lane]; 16 KB

  const int tid = threadIdx.x;
  const int wave = tid >> 6;      // 0..7 compute, 8..9 i2o/store
  const int lane = tid & 63;
  const int g = lane >> 4;
  const int n16 = lane & 15;
  const int bid = ((blockIdx.x & 7) << 5) | (blockIdx.x >> 3);  // XCD swizzle
  const int b0 = bid * BT;

  if (wave < 8) {
    // ================= COMPUTE WAVES: i2h + tanh + x staging ================
    // (no global stores, branch-free loop -> clean counted vmcnt on x loads)
    s16x8 W[8];
#pragma unroll
    for (int kt = 0; kt < 8; ++kt) {
      const float* wr = Wi2h + (size_t)(16 * wave + n16) * (IN_SZ + HID);
      s16x8 w8;
#pragma unroll
      for (int j = 0; j < 8; ++j)
        w8[j] = (short)f2bf(wr[32 * kt + KOFF(g, j)]);
      W[kt] = w8;
    }
    f32x4 bhv;
#pragma unroll
    for (int r = 0; r < 4; ++r) bhv[r] = bi2h[16 * wave + 4 * g + r];

    // loader mapping (validated R12): rows 2*lrb, 2*lrb+1 at col lc; tid<512
    const int lc = tid & 7;
    const int lrb = tid >> 3;                 // 0..63
    const int R0 = 2 * lrb;
    const int skk = R0 >> 5;
    const int r5 = R0 & 31;
    const int sg = (r5 < 16) ? (r5 >> 2) : ((r5 - 16) >> 2);
    const int sq = ((r5 & 2) >> 1) + ((r5 < 16) ? 0 : 2);
    const int slane = (sg << 4) | lc;
    const char* const xB = (const char*)x;
    const uint32_t xrb0 = ((uint32_t)R0 * (uint32_t)SB + (uint32_t)(b0 + lc)) * 4u;
    const uint32_t xrb1 = ((uint32_t)(R0 + 1) * (uint32_t)SB + (uint32_t)(b0 + lc)) * 4u;

    // stage x_0, h_0 into buf 0
    {
      float v0 = *(const float*)(xB + xrb0);
      float v1 = *(const float*)(xB + xrb1);
      ((uint32_t*)&sF[0][skk][slane])[sq] = pk2bf(v0, v1);
      uint32_t h0o = (uint32_t)R0 * (uint32_t)BATCH + (uint32_t)(b0 + lc);
      uint32_t h1o = (uint32_t)(R0 + 1) * (uint32_t)BATCH + (uint32_t)(b0 + lc);
      float hv0 = hidden[(size_t)h0o] * mask[(size_t)h0o];
      float hv1 = hidden[(size_t)h1o] * mask[(size_t)h1o];
      ((uint32_t*)&sF[0][4 + skk][slane])[sq] = pk2bf(hv0, hv1);
    }
    // 4 named prefetch buffers: xq0..xq3 = x_1..x_4 (consume-then-overwrite)
    float xq0[2], xq1[2], xq2[2], xq3[2];
    xq0[0] = *(const float*)(xB + xrb0 + 1u * BATCH * 4u);
    xq0[1] = *(const float*)(xB + xrb1 + 1u * BATCH * 4u);
    xq1[0] = *(const float*)(xB + xrb0 + 2u * BATCH * 4u);
    xq1[1] = *(const float*)(xB + xrb1 + 2u * BATCH * 4u);
    xq2[0] = *(const float*)(xB + xrb0 + 3u * BATCH * 4u);
    xq2[1] = *(const float*)(xB + xrb1 + 3u * BATCH * 4u);
    xq3[0] = *(const float*)(xB + xrb0 + 4u * BATCH * 4u);
    xq3[1] = *(const float*)(xB + xrb1 + 4u * BATCH * 4u);
    frag_barrier();

    uint32_t* const hdst0 = (uint32_t*)&sF[0][4 + (wave >> 1)][lane] + (wave & 1) * 2;
    uint32_t* const hdst1 = (uint32_t*)&sF[1][4 + (wave >> 1)][lane] + (wave & 1) * 2;

#define STEPC(T, P, XQ)                                                         \
  {                                                                             \
    const int t = (T);                                                          \
    const int pn = (P) ^ 1;                                                     \
    /* stage x_{t+1} from XQ (loaded 4 steps ago); reissue x_{t+5} */           \
    ((uint32_t*)&sF[pn][skk][slane])[sq] = pk2bf(XQ[0], XQ[1]);                 \
    {                                                                           \
      const uint32_t tn = (uint32_t)((t + 5 > 511) ? 511 : t + 5) * (BATCH * 4u); \
      XQ[0] = *(const float*)(xB + xrb0 + tn);                                  \
      XQ[1] = *(const float*)(xB + xrb1 + tn);                                  \
    }                                                                           \
    /* frags of [x_t ; h_t] from buf P */                                       \
    s16x8 X0 = sF[P][0][lane], X1 = sF[P][1][lane];                             \
    s16x8 X2 = sF[P][2][lane], X3 = sF[P][3][lane];                             \
    s16x8 H0 = sF[P][4][lane], H1 = sF[P][5][lane];                             \
    s16x8 H2 = sF[P][6][lane], H3 = sF[P][7][lane];                             \
    /* i2h: 4 independent chains of depth 2 */                                  \
    f32x4 a = bhv, a2 = {0.f, 0.f, 0.f, 0.f};                                   \
    f32x4 ax = {0.f, 0.f, 0.f, 0.f}, ax2 = {0.f, 0.f, 0.f, 0.f};                \
    mfma16(a, W[4], H0);   mfma16(a2, W[5], H1);                                \
    mfma16(ax, W[0], X0);  mfma16(ax2, W[1], X1);                               \
    mfma16(a, W[6], H2);   mfma16(a2, W[7], H3);                                \
    mfma16(ax, W[2], X2);  mfma16(ax2, W[3], X3);                               \
    /* h_{t+1} = tanh(sum); publish half-frag (D-frag == B-frag identity) */    \
    {                                                                           \
      f32x4 s0 = (a + a2) + (ax + ax2);                                         \
      uint32_t hp[2];                                                           \
      hp[0] = pk2bf(fast_tanh(s0[0]), fast_tanh(s0[1]));                        \
      hp[1] = pk2bf(fast_tanh(s0[2]), fast_tanh(s0[3]));                        \
      *(uint64_t*)(pn ? hdst1 : hdst0) = *(uint64_t*)hp;                        \
    }                                                                           \
    frag_barrier();                                                             \
  }

    for (int t4 = 0; t4 < SEQ; t4 += 4) {
      STEPC(t4 + 0, 0, xq0)
      STEPC(t4 + 1, 1, xq1)
      STEPC(t4 + 2, 0, xq2)
      STEPC(t4 + 3, 1, xq3)
    }
#undef STEPC
    // compute waves done: 1 + 512 barriers total

  } else {
    // ================= I2O/STORE WAVES: never wait on vmcnt ================
    const int ow = wave - 8;            // 0 -> tiles 0,1,2 ; 1 -> tiles 3,4
    s16x8 wO[3][4];
    f32x4 bov[3];
    uint32_t ybase[3];
    bool tvalid[3];
#pragma unroll
    for (int ot = 0; ot < 3; ++ot) {
      const int tk = 3 * ow + ot;
      tvalid[ot] = (tk < 5);
#pragma unroll
      for (int kk = 0; kk < 4; ++kk) {
        s16x8 a;
#pragma unroll
        for (int j = 0; j < 8; ++j) {
          int m = 16 * tk + n16;
          a[j] = (short)((tvalid[ot] && m < OUT_SZ)
                         ? f2bf(Wi2o[(size_t)m * HID + 32 * kk + KOFF(g, j)]) : 0);
        }
        wO[ot][kk] = a;
      }
#pragma unroll
      for (int r = 0; r < 4; ++r) {
        int m = 16 * tk + 4 * g + r;
        bov[ot][r] = (tvalid[ot] && m < OUT_SZ) ? bi2o[m] : 0.f;
      }
      ybase[ot] = (uint32_t)(16 * tk + 4 * g) * (uint32_t)SB + (uint32_t)(b0 + n16);
    }

    frag_barrier();   // prologue barrier (matches compute)
    frag_barrier();   // interval t = 0: no output yet

    for (int t = 1; t < SEQ; ++t) {
      const int P = t & 1;
      s16x8 H0 = sF[P][4][lane], H1 = sF[P][5][lane];
      s16x8 H2 = sF[P][6][lane], H3 = sF[P][7][lane];
      const uint32_t ty = (uint32_t)(t - 1) * (uint32_t)BATCH;
#pragma unroll
      for (int ot = 0; ot < 3; ++ot) {
        if (tvalid[ot]) {
          const int tk = 3 * ow + ot;
          f32x4 ao = bov[ot];
          mfma16(ao, wO[ot][0], H0); mfma16(ao, wO[ot][1], H1);
          mfma16(ao, wO[ot][2], H2); mfma16(ao, wO[ot][3], H3);
          if (n16 < BT) {
#pragma unroll
            for (int r = 0; r < 4; ++r)
              if (16 * tk + 4 * g + r < OUT_SZ)
                Y[(size_t)(ybase[ot] + (uint32_t)r * SB + ty)] = fmaxf(ao[r], 0.f);
          }
        }
      }
      frag_barrier();
    }
    // 1 + 1 + 511 = 513 barriers: matches compute. Epilogue: y_511 (buf 0).
    {
      s16x8 H0 = sF[0][4][lane], H1 = sF[0][5][lane];
      s16x8 H2 = sF[0][6][lane], H3 = sF[0][7][lane];
      const uint32_t ty = 511u * (uint32_t)BATCH;
#pragma unroll
      for (int ot = 0; ot < 3; ++ot) {
        if (tvalid[ot]) {
          const int tk = 3 * ow + ot;
          f32x4 ao = bov[ot];
          mfma16(ao, wO[ot][0], H0); mfma16(ao, wO[ot][1], H1);
          mfma16(ao, wO[ot][2], H2); mfma16(ao, wO[ot][3], H3);
          if (n16 < BT) {
#pragma unroll
            for (int r = 0; r < 4; ++r)
              if (16 * tk + 4 * g + r < OUT_SZ)
                Y[(size_t)(ybase[ot] + (uint32_t)r * SB + ty)] = fmaxf(ao[r], 0.f);
          }
        }
      }
    }
  }
}

extern "C" void kernel_launch(void* const* d_in, const int* in_sizes, int n_in,
                              void* d_out, int out_size, void* d_ws, size_t ws_size,
                              hipStream_t stream) {
  const float* x      = (const float*)d_in[0];
  const float* hidden = (const float*)d_in[1];
  const float* mask   = (const float*)d_in[2];
  const float* Wi2h   = (const float*)d_in[3];
  const float* bi2h   = (const float*)d_in[4];
  const float* Wi2o   = (const float*)d_in[5];
  const float* bi2o   = (const float*)d_in[6];
  float* Y = (float*)d_out;
  (void)in_sizes; (void)n_in; (void)out_size; (void)d_ws; (void)ws_size;
  rnn_kernel<<<dim3(BATCH / BT), dim3(NTHR), 0, stream>>>(
      x, hidden, mask, Wi2h, bi2h, Wi2o, bi2o, Y);
}

// Round 16
// 482.552 us; speedup vs baseline: 1.3966x; 1.0742x over previous
//
#include <hip/hip_runtime.h>
#include <hip/hip_bf16.h>
#include <stdint.h>

#define IN_SZ 128
#define HID 128
#define OUT_SZ 67
#define SEQ 512
#define BATCH 2048
#define BT 8
#define NTHR 768   // 8 pure-compute waves + 4 service waves
#define SB (SEQ * BATCH)   // 1048576

typedef __attribute__((ext_vector_type(4))) float f32x4;
typedef __attribute__((ext_vector_type(8))) short s16x8;
typedef __attribute__((ext_vector_type(8))) __bf16 bf16x8;

static __device__ __forceinline__ unsigned short f2bf(float f) {
  union { float f; uint32_t u; } c; c.f = f;
  uint32_t u = c.u;
  uint32_t r = u + 0x7FFFu + ((u >> 16) & 1u);
  return (unsigned short)(r >> 16);
}
static __device__ __forceinline__ uint32_t pk2bf(float lo, float hi) {
  __hip_bfloat162 h2 = __float22bfloat162_rn(float2{lo, hi});
  union { __hip_bfloat162 h; uint32_t u; } c; c.h = h2;
  return c.u;
}
static __device__ __forceinline__ float fast_tanh(float x) {
  float e = __builtin_amdgcn_exp2f(x * 2.885390081777927f);
  float r = __builtin_amdgcn_rcpf(e + 1.f);
  return __builtin_fmaf(-2.f, r, 1.f);
}
static __device__ __forceinline__ void mfma16(f32x4& c, s16x8 a, s16x8 b) {
  c = __builtin_amdgcn_mfma_f32_16x16x32_bf16(
        __builtin_bit_cast(bf16x8, a), __builtin_bit_cast(bf16x8, b), c, 0, 0, 0);
}
#define KOFF(g, j) (4 * (g) + ((j) & 3) + (((j) >> 2) << 4))

// clobber-free barrier (validated R9-R15): lgkm-only drain, vm ops float across;
// sched fences keep ds ops from migrating across (rule-18 hygiene).
static __device__ __forceinline__ void frag_barrier() {
  __builtin_amdgcn_sched_barrier(0);
  asm volatile("s_waitcnt lgkmcnt(0)");
  __builtin_amdgcn_s_barrier();
  __builtin_amdgcn_sched_barrier(0);
}

__global__ __launch_bounds__(NTHR, 1) void rnn_kernel(
    const float* __restrict__ x, const float* __restrict__ hidden,
    const float* __restrict__ mask, const float* __restrict__ Wi2h,
    const float* __restrict__ bi2h, const float* __restrict__ Wi2o,
    const float* __restrict__ bi2o, float* __restrict__ Y) {

  __shared__ s16x8 sX[3][4][64];   // x frags, triple ring (staged 2 ahead); 12 KB
  __shared__ s16x8 sH[2][4][64];   // h frags, double buffer; 8 KB

  const int tid = threadIdx.x;
  const int wave = tid >> 6;      // 0..7 compute, 8..11 service
  const int lane = tid & 63;
  const int g = lane >> 4;
  const int n16 = lane & 15;
  const int bid = ((blockIdx.x & 7) << 5) | (blockIdx.x >> 3);  // XCD swizzle
  const int b0 = bid * BT;

  if (wave < 8) {
    // ========== COMPUTE WAVES: pure {ds_read, MFMA, tanh, ds_write} ==========
    s16x8 W[8];
#pragma unroll
    for (int kt = 0; kt < 8; ++kt) {
      const float* wr = Wi2h + (size_t)(16 * wave + n16) * (IN_SZ + HID);
      s16x8 w8;
#pragma unroll
      for (int j = 0; j < 8; ++j)
        w8[j] = (short)f2bf(wr[32 * kt + KOFF(g, j)]);
      W[kt] = w8;
    }
    f32x4 bhv;
#pragma unroll
    for (int r = 0; r < 4; ++r) bhv[r] = bi2h[16 * wave + 4 * g + r];

    frag_barrier();   // matches service prologue barrier

    uint32_t* const hdst0 = (uint32_t*)&sH[0][wave >> 1][lane] + (wave & 1) * 2;
    uint32_t* const hdst1 = (uint32_t*)&sH[1][wave >> 1][lane] + (wave & 1) * 2;

    // CSTEP(K): t = t6+K; parity P = K&1 (t6 % 6 == 0), x slot S = K%3
#define CSTEP(K)                                                                \
  {                                                                             \
    const int P = (K) & 1;                                                      \
    const int S = (K) % 3;                                                      \
    s16x8 H0 = sH[P][0][lane], H1 = sH[P][1][lane];                             \
    s16x8 H2 = sH[P][2][lane], H3 = sH[P][3][lane];                             \
    s16x8 X0 = sX[S][0][lane], X1 = sX[S][1][lane];                             \
    s16x8 X2 = sX[S][2][lane], X3 = sX[S][3][lane];                             \
    f32x4 a = bhv, a2 = {0.f, 0.f, 0.f, 0.f};                                   \
    f32x4 ax = {0.f, 0.f, 0.f, 0.f}, ax2 = {0.f, 0.f, 0.f, 0.f};                \
    mfma16(a, W[4], H0);   mfma16(a2, W[5], H1);                                \
    mfma16(ax, W[0], X0);  mfma16(ax2, W[1], X1);                               \
    mfma16(a, W[6], H2);   mfma16(a2, W[7], H3);                                \
    mfma16(ax, W[2], X2);  mfma16(ax2, W[3], X3);                               \
    {                                                                           \
      f32x4 s0 = (a + a2) + (ax + ax2);                                         \
      uint32_t hp[2];                                                           \
      hp[0] = pk2bf(fast_tanh(s0[0]), fast_tanh(s0[1]));                        \
      hp[1] = pk2bf(fast_tanh(s0[2]), fast_tanh(s0[3]));                        \
      *(uint64_t*)(P ? hdst0 : hdst1) = *(uint64_t*)hp;                         \
    }                                                                           \
    frag_barrier();                                                             \
  }

    for (int t6 = 0; t6 < 510; t6 += 6) {
      CSTEP(0) CSTEP(1) CSTEP(2) CSTEP(3) CSTEP(4) CSTEP(5)
    }
    CSTEP(0) CSTEP(1)   // t = 510 (P0,S0), t = 511 (P1,S1)
#undef CSTEP

  } else {
    // ========== SERVICE WAVES: x load+stage (2 ahead), i2o, Y stores ==========
    const int sv = wave - 8;                 // 0..3
    const int svl = (sv << 6) | lane;        // 0..255

    // ---- i2o tiles: sv0:{0,1} sv1:{2,3} sv2:{4} sv3:{} ----
    const int ntile = (sv < 2) ? 2 : (sv == 2 ? 1 : 0);
    const int tk0 = 2 * sv;
    s16x8 wO[2][4];
    f32x4 bov[2];
    uint32_t ybase[2];
#pragma unroll
    for (int ot = 0; ot < 2; ++ot) {
      const int tk = tk0 + ot;
      const bool tv = (ot < ntile);
#pragma unroll
      for (int kk = 0; kk < 4; ++kk) {
        s16x8 a;
#pragma unroll
        for (int j = 0; j < 8; ++j) {
          int m = 16 * tk + n16;
          a[j] = (short)((tv && m < OUT_SZ)
                         ? f2bf(Wi2o[(size_t)m * HID + 32 * kk + KOFF(g, j)]) : 0);
        }
        wO[ot][kk] = a;
      }
#pragma unroll
      for (int r = 0; r < 4; ++r) {
        int m = 16 * tk + 4 * g + r;
        bov[ot][r] = (tv && m < OUT_SZ) ? bi2o[m] : 0.f;
      }
      ybase[ot] = (uint32_t)(16 * tk + 4 * g) * (uint32_t)SB + (uint32_t)(b0 + n16);
    }

    // ---- x stage mapping: this lane owns frag-dwords d0 = 2*svl, d0+1 ----
    // dword d -> rowpair rp = d>>3, col lc = d&7; rows R0=2*rp, R0+1
    int skkA, sqA, slaneA, skkB, sqB, slaneB;
    uint32_t xaA0, xaA1, xaB0, xaB1;   // byte offsets of the 4 source floats
    {
      int d = 2 * svl;
      int rp = d >> 3, lc = d & 7, R0 = 2 * rp;
      int r5 = R0 & 31;
      int sg = (r5 < 16) ? (r5 >> 2) : ((r5 - 16) >> 2);
      skkA = R0 >> 5;
      sqA = ((r5 & 2) >> 1) + ((r5 < 16) ? 0 : 2);
      slaneA = (sg << 4) | lc;
      xaA0 = ((uint32_t)R0 * (uint32_t)SB + (uint32_t)(b0 + lc)) * 4u;
      xaA1 = ((uint32_t)(R0 + 1) * (uint32_t)SB + (uint32_t)(b0 + lc)) * 4u;
      d = 2 * svl + 1;
      rp = d >> 3; lc = d & 7; R0 = 2 * rp;
      r5 = R0 & 31;
      sg = (r5 < 16) ? (r5 >> 2) : ((r5 - 16) >> 2);
      skkB = R0 >> 5;
      sqB = ((r5 & 2) >> 1) + ((r5 < 16) ? 0 : 2);
      slaneB = (sg << 4) | lc;
      xaB0 = ((uint32_t)R0 * (uint32_t)SB + (uint32_t)(b0 + lc)) * 4u;
      xaB1 = ((uint32_t)(R0 + 1) * (uint32_t)SB + (uint32_t)(b0 + lc)) * 4u;
    }
    const char* const xB = (const char*)x;

    // ---- prologue: stage x0 -> sX[0], x1 -> sX[1], h0 -> sH[0] ----
#pragma unroll
    for (int tt = 0; tt < 2; ++tt) {
      const uint32_t to = (uint32_t)tt * (BATCH * 4u);
      float a0 = *(const float*)(xB + xaA0 + to);
      float a1 = *(const float*)(xB + xaA1 + to);
      float c0 = *(const float*)(xB + xaB0 + to);
      float c1 = *(const float*)(xB + xaB1 + to);
      ((uint32_t*)&sX[tt][skkA][slaneA])[sqA] = pk2bf(a0, a1);
      ((uint32_t*)&sX[tt][skkB][slaneB])[sqB] = pk2bf(c0, c1);
    }
    {
      // h0 = hidden*mask through the same dword mapping (x layout -> h layout)
      const uint32_t hA0 = (xaA0 / (4u * SB)) * (uint32_t)BATCH + (uint32_t)(b0 + ((2 * svl) & 7));
      const uint32_t hA1 = (xaA1 / (4u * SB)) * (uint32_t)BATCH + (uint32_t)(b0 + ((2 * svl) & 7));
      const uint32_t hB0 = (xaB0 / (4u * SB)) * (uint32_t)BATCH + (uint32_t)(b0 + ((2 * svl + 1) & 7));
      const uint32_t hB1 = (xaB1 / (4u * SB)) * (uint32_t)BATCH + (uint32_t)(b0 + ((2 * svl + 1) & 7));
      float a0 = hidden[(size_t)hA0] * mask[(size_t)hA0];
      float a1 = hidden[(size_t)hA1] * mask[(size_t)hA1];
      float c0 = hidden[(size_t)hB0] * mask[(size_t)hB0];
      float c1 = hidden[(size_t)hB1] * mask[(size_t)hB1];
      ((uint32_t*)&sH[0][skkA][slaneA])[sqA] = pk2bf(a0, a1);
      ((uint32_t*)&sH[0][skkB][slaneB])[sqB] = pk2bf(c0, c1);
    }
    // ---- 6 named raw buffers: xq[K] holds x(t6+K+2); 6-interval load slack ----
    float q0[4], q1[4], q2[4], q3[4], q4[4], q5[4];
#define FILLQ(Q, T)                                                             \
    {                                                                           \
      const uint32_t to = (uint32_t)(T) * (BATCH * 4u);                         \
      Q[0] = *(const float*)(xB + xaA0 + to);                                   \
      Q[1] = *(const float*)(xB + xaA1 + to);                                   \
      Q[2] = *(const float*)(xB + xaB0 + to);                                   \
      Q[3] = *(const float*)(xB + xaB1 + to);                                   \
    }
    FILLQ(q0, 2) FILLQ(q1, 3) FILLQ(q2, 4) FILLQ(q3, 5) FILLQ(q4, 6) FILLQ(q5, 7)
    frag_barrier();

    // SSTEP(K, Q): t = t6+K; stage x(t+2) from Q -> sX[(K+2)%3]; reload Q = x(t+8);
    // i2o(t-1) from sH[K&1]; barrier.
#define SSTEP(K, Q)                                                             \
  {                                                                             \
    const int t = t6 + (K);                                                     \
    const int SW = ((K) + 2) % 3;                                               \
    ((uint32_t*)&sX[SW][skkA][slaneA])[sqA] = pk2bf(Q[0], Q[1]);                \
    ((uint32_t*)&sX[SW][skkB][slaneB])[sqB] = pk2bf(Q[2], Q[3]);                \
    {                                                                           \
      const int tn = (t + 8 > 511) ? 511 : t + 8;                               \
      FILLQ(Q, tn)                                                              \
    }                                                                           \
    if (ntile > 0 && t > 0) {                                                   \
      const int P = (K) & 1;                                                    \
      s16x8 H0 = sH[P][0][lane], H1 = sH[P][1][lane];                           \
      s16x8 H2 = sH[P][2][lane], H3 = sH[P][3][lane];                           \
      const uint32_t ty = (uint32_t)(t - 1) * (uint32_t)BATCH;                  \
      _Pragma("unroll")                                                         \
      for (int ot = 0; ot < 2; ++ot) {                                          \
        if (ot < ntile) {                                                       \
          const int tk = tk0 + ot;                                              \
          f32x4 ao = bov[ot];                                                   \
          mfma16(ao, wO[ot][0], H0); mfma16(ao, wO[ot][1], H1);                 \
          mfma16(ao, wO[ot][2], H2); mfma16(ao, wO[ot][3], H3);                 \
          if (n16 < BT) {                                                       \
            _Pragma("unroll")                                                   \
            for (int r = 0; r < 4; ++r)                                         \
              if (16 * tk + 4 * g + r < OUT_SZ)                                 \
                Y[(size_t)(ybase[ot] + (uint32_t)r * SB + ty)] = fmaxf(ao[r], 0.f); \
          }                                                                     \
        }                                                                       \
      }                                                                         \
    }                                                                           \
    frag_barrier();                                                             \
  }

    for (int t6 = 0; t6 < 510; t6 += 6) {
      SSTEP(0, q0) SSTEP(1, q1) SSTEP(2, q2) SSTEP(3, q3) SSTEP(4, q4) SSTEP(5, q5)
    }
    {
      const int t6 = 510;
      SSTEP(0, q0) SSTEP(1, q1)   // t = 510, 511
    }
#undef SSTEP
#undef FILLQ

    // ---- epilogue: y_511 from h_512 (sH[0]) ----
    if (ntile > 0) {
      s16x8 H0 = sH[0][0][lane], H1 = sH[0][1][lane];
      s16x8 H2 = sH[0][2][lane], H3 = sH[0][3][lane];
      const uint32_t ty = 511u * (uint32_t)BATCH;
#pragma unroll
      for (int ot = 0; ot < 2; ++ot) {
        if (ot < ntile) {
          const int tk = tk0 + ot;
          f32x4 ao = bov[ot];
          mfma16(ao, wO[ot][0], H0); mfma16(ao, wO[ot][1], H1);
          mfma16(ao, wO[ot][2], H2); mfma16(ao, wO[ot][3], H3);
          if (n16 < BT) {
#pragma unroll
            for (int r = 0; r < 4; ++r)
              if (16 * tk + 4 * g + r < OUT_SZ)
                Y[(size_t)(ybase[ot] + (uint32_t)r * SB + ty)] = fmaxf(ao[r], 0.f);
          }
        }
      }
    }
  }
}

extern "C" void kernel_launch(void* const* d_in, const int* in_sizes, int n_in,
                              void* d_out, int out_size, void* d_ws, size_t ws_size,
                              hipStream_t stream) {
  const float* x      = (const float*)d_in[0];
  const float* hidden = (const float*)d_in[1];
  const float* mask   = (const float*)d_in[2];
  const float* Wi2h   = (const float*)d_in[3];
  const float* bi2h   = (const float*)d_in[4];
  const float* Wi2o   = (const float*)d_in[5];
  const float* bi2o   = (const float*)d_in[6];
  float* Y = (float*)d_out;
  (void)in_sizes; (void)n_in; (void)out_size; (void)d_ws; (void)ws_size;
  rnn_kernel<<<dim3(BATCH / BT), dim3(NTHR), 0, stream>>>(
      x, hidden, mask, Wi2h, bi2h, Wi2o, bi2o, Y);
}

// Round 17
// 412.954 us; speedup vs baseline: 1.6320x; 1.1685x over previous
//
#include <hip/hip_runtime.h>
#include <hip/hip_bf16.h>
#include <stdint.h>

#define IN_SZ 128
#define HID 128
#define OUT_SZ 67
#define SEQ 512
#define BATCH 2048
#define BT 8
#define NTHR 384   // 4 compute waves (2 tiles each) + 2 service waves (x only)
#define SB (SEQ * BATCH)   // 1048576

typedef __attribute__((ext_vector_type(4))) float f32x4;
typedef __attribute__((ext_vector_type(8))) short s16x8;
typedef __attribute__((ext_vector_type(8))) __bf16 bf16x8;

static __device__ __forceinline__ unsigned short f2bf(float f) {
  union { float f; uint32_t u; } c; c.f = f;
  uint32_t u = c.u;
  uint32_t r = u + 0x7FFFu + ((u >> 16) & 1u);
  return (unsigned short)(r >> 16);
}
static __device__ __forceinline__ uint32_t pk2bf(float lo, float hi) {
  __hip_bfloat162 h2 = __float22bfloat162_rn(float2{lo, hi});
  union { __hip_bfloat162 h; uint32_t u; } c; c.h = h2;
  return c.u;
}
static __device__ __forceinline__ float fast_tanh(float x) {
  float e = __builtin_amdgcn_exp2f(x * 2.885390081777927f);
  float r = __builtin_amdgcn_rcpf(e + 1.f);
  return __builtin_fmaf(-2.f, r, 1.f);
}
static __device__ __forceinline__ void mfma16(f32x4& c, s16x8 a, s16x8 b) {
  c = __builtin_amdgcn_mfma_f32_16x16x32_bf16(
        __builtin_bit_cast(bf16x8, a), __builtin_bit_cast(bf16x8, b), c, 0, 0, 0);
}
#define KOFF(g, j) (4 * (g) + ((j) & 3) + (((j) >> 2) << 4))

// clobber-free barrier (validated R9-R16): lgkm-only drain, vm ops float across
static __device__ __forceinline__ void frag_barrier() {
  __builtin_amdgcn_sched_barrier(0);
  asm volatile("s_waitcnt lgkmcnt(0)");
  __builtin_amdgcn_s_barrier();
  __builtin_amdgcn_sched_barrier(0);
}

__global__ __launch_bounds__(NTHR, 1) void rnn_kernel(
    const float* __restrict__ x, const float* __restrict__ hidden,
    const float* __restrict__ mask, const float* __restrict__ Wi2h,
    const float* __restrict__ bi2h, const float* __restrict__ Wi2o,
    const float* __restrict__ bi2o, float* __restrict__ Y) {

  __shared__ s16x8 sX[3][4][64];   // x frags, triple ring (staged 2 ahead); 12 KB
  __shared__ s16x8 sH[2][4][64];   // h frags, double buffer; 8 KB

  const int tid = threadIdx.x;
  const int wave = tid >> 6;      // 0..3 compute (tiles 2w,2w+1), 4..5 service
  const int lane = tid & 63;
  const int g = lane >> 4;
  const int n16 = lane & 15;
  const int bid = ((blockIdx.x & 7) << 5) | (blockIdx.x >> 3);  // XCD swizzle
  const int b0 = bid * BT;

  if (wave < 4) {
    // ===== COMPUTE: i2h (2 tiles) + tanh + i2o + stores; NO global loads =====
    s16x8 W0[8], W1[8];
#pragma unroll
    for (int kt = 0; kt < 8; ++kt) {
      const float* wr0 = Wi2h + (size_t)(16 * (2 * wave + 0) + n16) * (IN_SZ + HID);
      const float* wr1 = Wi2h + (size_t)(16 * (2 * wave + 1) + n16) * (IN_SZ + HID);
      s16x8 w8a, w8b;
#pragma unroll
      for (int j = 0; j < 8; ++j) {
        w8a[j] = (short)f2bf(wr0[32 * kt + KOFF(g, j)]);
        w8b[j] = (short)f2bf(wr1[32 * kt + KOFF(g, j)]);
      }
      W0[kt] = w8a; W1[kt] = w8b;
    }
    f32x4 bhv0, bhv1;
#pragma unroll
    for (int r = 0; r < 4; ++r) {
      bhv0[r] = bi2h[16 * (2 * wave + 0) + 4 * g + r];
      bhv1[r] = bi2h[16 * (2 * wave + 1) + 4 * g + r];
    }

    // out-tiles: waves 0..2 -> {wave}; wave 3 -> {3, 4}
    const int nt = (wave == 3) ? 2 : 1;
    s16x8 wO[2][4];
    f32x4 bov[2];
    uint32_t ybase[2];
    int trow[2];
#pragma unroll
    for (int ot = 0; ot < 2; ++ot) {
      const int tk = (ot == 0) ? wave : 4;
      const bool tv = (ot < ((wave == 3) ? 2 : 1));
#pragma unroll
      for (int kk = 0; kk < 4; ++kk) {
        s16x8 a;
#pragma unroll
        for (int j = 0; j < 8; ++j) {
          int m = 16 * tk + n16;
          a[j] = (short)((tv && m < OUT_SZ)
                         ? f2bf(Wi2o[(size_t)m * HID + 32 * kk + KOFF(g, j)]) : 0);
        }
        wO[ot][kk] = a;
      }
#pragma unroll
      for (int r = 0; r < 4; ++r) {
        int m = 16 * tk + 4 * g + r;
        bov[ot][r] = (tv && m < OUT_SZ) ? bi2o[m] : 0.f;
      }
      ybase[ot] = (uint32_t)(16 * tk + 4 * g) * (uint32_t)SB + (uint32_t)(b0 + n16);
      trow[ot] = 16 * tk + 4 * g;
    }

    // stage h0 frag `wave` (rows 32w + KOFF(g,j), col clamped for garbage lanes)
    {
      const int cc = (b0 + n16 < BATCH) ? (b0 + n16) : (BATCH - 1);
      union { s16x8 v; uint32_t d[4]; } u;
#pragma unroll
      for (int q = 0; q < 4; ++q) {
        int r0 = 32 * wave + KOFF(g, 2 * q);
        int r1 = 32 * wave + KOFF(g, 2 * q + 1);
        float h0 = hidden[(size_t)r0 * BATCH + cc] * mask[(size_t)r0 * BATCH + cc];
        float h1 = hidden[(size_t)r1 * BATCH + cc] * mask[(size_t)r1 * BATCH + cc];
        u.d[q] = pk2bf(h0, h1);
      }
      sH[0][wave][lane] = u.v;
    }
    frag_barrier();

    // CSTEP(K): t = t6+K; parity P = K&1, x slot S = K%3 (t6 % 6 == 0)
#define CSTEP(K)                                                                \
  {                                                                             \
    const int t = t6 + (K);                                                     \
    const int P = (K) & 1;                                                      \
    const int S = (K) % 3;                                                      \
    s16x8 X0 = sX[S][0][lane], X1 = sX[S][1][lane];                             \
    s16x8 X2 = sX[S][2][lane], X3 = sX[S][3][lane];                             \
    s16x8 H0 = sH[P][0][lane], H1 = sH[P][1][lane];                             \
    s16x8 H2 = sH[P][2][lane], H3 = sH[P][3][lane];                             \
    f32x4 a = bhv0, a2 = {0.f, 0.f, 0.f, 0.f};                                  \
    f32x4 b = bhv1, b2 = {0.f, 0.f, 0.f, 0.f};                                  \
    mfma16(a, W0[0], X0);  mfma16(a2, W0[1], X1);                               \
    mfma16(b, W1[0], X0);  mfma16(b2, W1[1], X1);                               \
    mfma16(a, W0[2], X2);  mfma16(a2, W0[3], X3);                               \
    mfma16(b, W1[2], X2);  mfma16(b2, W1[3], X3);                               \
    mfma16(a, W0[4], H0);  mfma16(a2, W0[5], H1);                               \
    mfma16(b, W1[4], H0);  mfma16(b2, W1[5], H1);                               \
    mfma16(a, W0[6], H2);  mfma16(a2, W0[7], H3);                               \
    mfma16(b, W1[6], H2);  mfma16(b2, W1[7], H3);                               \
    /* tanh + publish full frag `wave` (D-frag(2w,2w+1) == B-frag w) */         \
    {                                                                           \
      f32x4 s0 = a + a2, s1 = b + b2;                                           \
      union { s16x8 v; uint32_t d[4]; } u;                                      \
      u.d[0] = pk2bf(fast_tanh(s0[0]), fast_tanh(s0[1]));                       \
      u.d[1] = pk2bf(fast_tanh(s0[2]), fast_tanh(s0[3]));                       \
      u.d[2] = pk2bf(fast_tanh(s1[0]), fast_tanh(s1[1]));                       \
      u.d[3] = pk2bf(fast_tanh(s1[2]), fast_tanh(s1[3]));                       \
      sH[P ^ 1][wave][lane] = u.v;                                              \
    }                                                                           \
    /* i2o(t-1) on in-register H; stores fire-and-forget (no loads in loop) */  \
    if (t > 0) {                                                                \
      const uint32_t ty = (uint32_t)(t - 1) * (uint32_t)BATCH;                  \
      _Pragma("unroll")                                                         \
      for (int ot = 0; ot < 2; ++ot) {                                          \
        if (ot < nt) {                                                          \
          f32x4 ao = bov[ot];                                                   \
          mfma16(ao, wO[ot][0], H0); mfma16(ao, wO[ot][1], H1);                 \
          mfma16(ao, wO[ot][2], H2); mfma16(ao, wO[ot][3], H3);                 \
          if (n16 < BT) {                                                       \
            _Pragma("unroll")                                                   \
            for (int r = 0; r < 4; ++r)                                         \
              if (trow[ot] + r < OUT_SZ)                                        \
                Y[(size_t)(ybase[ot] + (uint32_t)r * SB + ty)] = fmaxf(ao[r], 0.f); \
          }                                                                     \
        }                                                                       \
      }                                                                         \
    }                                                                           \
    frag_barrier();                                                             \
  }

    for (int t6 = 0; t6 < 510; t6 += 6) {
      CSTEP(0) CSTEP(1) CSTEP(2) CSTEP(3) CSTEP(4) CSTEP(5)
    }
    {
      const int t6 = 510;
      CSTEP(0) CSTEP(1)   // t = 510, 511
    }
#undef CSTEP

    // epilogue: y_511 from h_512 (published into sH[0] at t=511)
    {
      s16x8 H0 = sH[0][0][lane], H1 = sH[0][1][lane];
      s16x8 H2 = sH[0][2][lane], H3 = sH[0][3][lane];
      const uint32_t ty = 511u * (uint32_t)BATCH;
#pragma unroll
      for (int ot = 0; ot < 2; ++ot) {
        if (ot < nt) {
          f32x4 ao = bov[ot];
          mfma16(ao, wO[ot][0], H0); mfma16(ao, wO[ot][1], H1);
          mfma16(ao, wO[ot][2], H2); mfma16(ao, wO[ot][3], H3);
          if (n16 < BT) {
#pragma unroll
            for (int r = 0; r < 4; ++r)
              if (trow[ot] + r < OUT_SZ)
                Y[(size_t)(ybase[ot] + (uint32_t)r * SB + ty)] = fmaxf(ao[r], 0.f);
          }
        }
      }
    }

  } else {
    // ===== SERVICE (2 waves): x load + stage into sX ring, 2 intervals ahead =====
    const int svl = ((wave - 4) << 6) | lane;   // 0..127
    const int rp = svl >> 1;                    // row-pair 0..63
    const int R0 = 2 * rp;                      // rows R0, R0+1
    const int lcb = (svl & 1) * 4;              // col base (4 cols per thread)
    const int skk = R0 >> 5;
    const int r5 = R0 & 31;
    const int sg = (r5 < 16) ? (r5 >> 2) : ((r5 - 16) >> 2);
    const int sq = ((r5 & 2) >> 1) + ((r5 < 16) ? 0 : 2);
    const int slb = sg << 4;
    const char* const xB = (const char*)x;
    const uint32_t xr0 = ((uint32_t)R0 * (uint32_t)SB + (uint32_t)b0) * 4u;
    const uint32_t xr1 = ((uint32_t)(R0 + 1) * (uint32_t)SB + (uint32_t)b0) * 4u;

    // prologue: stage x0 -> sX[0], x1 -> sX[1]
#pragma unroll
    for (int tt = 0; tt < 2; ++tt) {
      const uint32_t to = (uint32_t)tt * (BATCH * 4u);
#pragma unroll
      for (int i = 0; i < 4; ++i) {
        const int lc = lcb + i;
        float v0 = *(const float*)(xB + xr0 + to + 4u * lc);
        float v1 = *(const float*)(xB + xr1 + to + 4u * lc);
        ((uint32_t*)&sX[tt][skk][slb | lc])[sq] = pk2bf(v0, v1);
      }
    }
    // 6 named raw buffers: qK holds x(t6+K+2); reloaded 6 intervals ahead
    float q0[8], q1[8], q2[8], q3[8], q4[8], q5[8];
#define FILLQ(Q, T)                                                             \
    {                                                                           \
      const uint32_t to = (uint32_t)(T) * (BATCH * 4u);                         \
      _Pragma("unroll")                                                         \
      for (int i = 0; i < 4; ++i) {                                             \
        Q[2 * i]     = *(const float*)(xB + xr0 + to + 4u * (lcb + i));         \
        Q[2 * i + 1] = *(const float*)(xB + xr1 + to + 4u * (lcb + i));         \
      }                                                                         \
    }
    FILLQ(q0, 2) FILLQ(q1, 3) FILLQ(q2, 4) FILLQ(q3, 5) FILLQ(q4, 6) FILLQ(q5, 7)
    frag_barrier();

#define SSTEP(K, Q)                                                             \
  {                                                                             \
    const int t = t6 + (K);                                                     \
    const int SW = ((K) + 2) % 3;                                               \
    _Pragma("unroll")                                                           \
    for (int i = 0; i < 4; ++i) {                                               \
      const int lc = lcb + i;                                                   \
      ((uint32_t*)&sX[SW][skk][slb | lc])[sq] = pk2bf(Q[2 * i], Q[2 * i + 1]);  \
    }                                                                           \
    {                                                                           \
      const int tn = (t + 8 > 511) ? 511 : t + 8;                               \
      FILLQ(Q, tn)                                                              \
    }                                                                           \
    frag_barrier();                                                             \
  }

    for (int t6 = 0; t6 < 510; t6 += 6) {
      SSTEP(0, q0) SSTEP(1, q1) SSTEP(2, q2) SSTEP(3, q3) SSTEP(4, q4) SSTEP(5, q5)
    }
    {
      const int t6 = 510;
      SSTEP(0, q0) SSTEP(1, q1)   // t = 510, 511 -> barrier counts match compute
    }
#undef SSTEP
#undef FILLQ
  }
}

extern "C" void kernel_launch(void* const* d_in, const int* in_sizes, int n_in,
                              void* d_out, int out_size, void* d_ws, size_t ws_size,
                              hipStream_t stream) {
  const float* x      = (const float*)d_in[0];
  const float* hidden = (const float*)d_in[1];
  const float* mask   = (const float*)d_in[2];
  const float* Wi2h   = (const float*)d_in[3];
  const float* bi2h   = (const float*)d_in[4];
  const float* Wi2o   = (const float*)d_in[5];
  const float* bi2o   = (const float*)d_in[6];
  float* Y = (float*)d_out;
  (void)in_sizes; (void)n_in; (void)out_size; (void)d_ws; (void)ws_size;
  rnn_kernel<<<dim3(BATCH / BT), dim3(NTHR), 0, stream>>>(
      x, hidden, mask, Wi2h, bi2h, Wi2o, bi2o, Y);
}